// Round 8
// baseline (132.715 us; speedup 1.0000x reference)
//
#include <hip/hip_runtime.h>

// Problem: B=2048, D=512, all fp32.
// q = query@Wq.T+bq ; k,v likewise. attn[b,i,j]=q_i*k_j (rank-1!),
// softmax over j, out[b,i] = sum_j softmax_j(q_i*k_j)*v_j.
//
// Round 12 (single-variable: GEMM -> LDS-free; attn byte-identical to r11):
//  - GEMM REWRITE: no LDS, no barriers, no DMA. Each lane loads its MFMA
//    fragments DIRECTLY from global as 2x dwordx4 per fragment:
//    A[m=l15][k=quad*8+j] -> &X[(m0+wm+mi*16+l15)*512 + kk + quad*8].
//    Per load instr the wave touches 16 rows x 128 B fully-used lines
//    (quads 0..3 cover 128 B contiguous) -> 100% L1/L2 line utilization.
//    Total L2-side traffic ~200 MB (A re-read 8x across N-tiles, W 32x,
//    L3-backed) ~= 6 us chip-wide. Compiler pipelines loads across K-steps
//    (no sync anywhere); 12 waves/CU give TLP. In-register hi/lo split,
//    12 MFMA 3-term split-bf16 per step -- numerically identical to r10/r11
//    fragment-for-fragment, so absmax must stay 0.0078125.
//  - attn unchanged (64-pt grid eval of the per-batch tilted-mean f(s),
//    cubic interpolation; k*log2e at LDS staging).
//
// Ledger: ~43us poison fill + ~25-30us reset memsets/gaps are fixed harness
// cost inside the timed window; controllable = gemm + attn + 2 gaps.

#define B_SZ 2048
#define D_SZ 512
#define LOG2E 1.44269504088896340736f
#define NGRID 64
#define SEG 136   // 128 floats payload + 8 pad: segment s starts at bank 8s

typedef __attribute__((ext_vector_type(2))) float  f32x2;
typedef __attribute__((ext_vector_type(4))) float  f32x4;
typedef __attribute__((ext_vector_type(8))) short  bf16x8;   // MFMA A/B carrier

__device__ __forceinline__ float exp2_raw(float x) {
#if defined(__has_builtin) && __has_builtin(__builtin_amdgcn_exp2f)
    return __builtin_amdgcn_exp2f(x);
#else
    return exp2f(x);
#endif
}

// Forced packed fp32 math (compiler emits scalar for f32x2 exprs otherwise).
__device__ __forceinline__ f32x2 pk_fma(f32x2 a, f32x2 b, f32x2 c) {
    f32x2 d;
    asm("v_pk_fma_f32 %0, %1, %2, %3" : "=v"(d) : "v"(a), "v"(b), "v"(c));
    return d;
}
__device__ __forceinline__ f32x2 pk_add(f32x2 a, f32x2 b) {
    f32x2 d;
    asm("v_pk_add_f32 %0, %1, %2" : "=v"(d) : "v"(a), "v"(b));
    return d;
}
__device__ __forceinline__ f32x2 pk_mul(f32x2 a, f32x2 b) {
    f32x2 d;
    asm("v_pk_mul_f32 %0, %1, %2" : "=v"(d) : "v"(a), "v"(b));
    return d;
}

// Truncation split: hi = top 16 bits of fp32; lo = bf16(trunc) of residual.
// |x - hi - lo| <= 2^-14 |x|
__device__ __forceinline__ void split1(float x, unsigned short& hi, unsigned short& lo) {
    unsigned int u = __float_as_uint(x);
    hi = (unsigned short)(u >> 16);
    float r = x - __uint_as_float(u & 0xFFFF0000u);
    lo = (unsigned short)(__float_as_uint(r) >> 16);
}

// 8 fp32 (two f32x4, k ascending) -> hi/lo bf16x8 fragments
__device__ __forceinline__ void split8(const f32x4 p0, const f32x4 p1,
                                       bf16x8& h, bf16x8& l) {
    unsigned short hh, ll;
    split1(p0.x, hh, ll); h[0] = (short)hh; l[0] = (short)ll;
    split1(p0.y, hh, ll); h[1] = (short)hh; l[1] = (short)ll;
    split1(p0.z, hh, ll); h[2] = (short)hh; l[2] = (short)ll;
    split1(p0.w, hh, ll); h[3] = (short)hh; l[3] = (short)ll;
    split1(p1.x, hh, ll); h[4] = (short)hh; l[4] = (short)ll;
    split1(p1.y, hh, ll); h[5] = (short)hh; l[5] = (short)ll;
    split1(p1.z, hh, ll); h[6] = (short)hh; l[6] = (short)ll;
    split1(p1.w, hh, ll); h[7] = (short)hh; l[7] = (short)ll;
}

// ---------------------------------------------------------------------------
// Kernel 1: Y = X @ W^T + bias via split-bf16 MFMA, LDS-free.
// 64x64 tile per block, 256 thr = 4 waves (2x2, each wave an independent
// 32x32 via 2x2 frags of 16x16x32). Fragments loaded straight from global
// (2x dwordx4 each), split to hi/lo bf16 in registers, 12 MFMA per K-step.
// No LDS, no barriers -- loads pipeline freely across the 16 K-steps.
// ---------------------------------------------------------------------------
__global__ __launch_bounds__(256) void qkv_gemm_mfma(
    const float* __restrict__ Xq, const float* __restrict__ Xk, const float* __restrict__ Xv,
    const float* __restrict__ Wq, const float* __restrict__ Wk, const float* __restrict__ Wv,
    const float* __restrict__ bq, const float* __restrict__ bk, const float* __restrict__ bv,
    float* __restrict__ qkv_out)
{
    const int which = blockIdx.z;
    const float* __restrict__ X    = (which == 0) ? Xq : (which == 1) ? Xk : Xv;
    const float* __restrict__ W    = (which == 0) ? Wq : (which == 1) ? Wk : Wv;
    const float* __restrict__ bias = (which == 0) ? bq : (which == 1) ? bk : bv;
    float* __restrict__ Y = qkv_out + (size_t)which * B_SZ * D_SZ;

    const int t    = threadIdx.x;
    const int lane = t & 63;
    const int wv   = t >> 6;
    const int l15  = lane & 15;
    const int quad = lane >> 4;
    const int wm   = (wv >> 1) * 32;
    const int wn   = (wv & 1) * 32;
    const int m0   = blockIdx.x * 64;
    const int n0   = blockIdx.y * 64;

    f32x4 acc[2][2] = {};

    // per-lane fragment row pointers (k advances along the row)
    const float* A0 = X + (size_t)(m0 + wm + l15) * D_SZ + quad * 8;        // mi=0
    const float* A1 = A0 + (size_t)16 * D_SZ;                               // mi=1
    const float* B0 = W + (size_t)(n0 + wn + l15) * D_SZ + quad * 8;        // ni=0
    const float* B1 = B0 + (size_t)16 * D_SZ;                               // ni=1

#pragma unroll 2
    for (int kk = 0; kk < D_SZ; kk += 32) {
        f32x4 a00 = *(const f32x4*)(A0 + kk);
        f32x4 a01 = *(const f32x4*)(A0 + kk + 4);
        f32x4 a10 = *(const f32x4*)(A1 + kk);
        f32x4 a11 = *(const f32x4*)(A1 + kk + 4);
        f32x4 b00 = *(const f32x4*)(B0 + kk);
        f32x4 b01 = *(const f32x4*)(B0 + kk + 4);
        f32x4 b10 = *(const f32x4*)(B1 + kk);
        f32x4 b11 = *(const f32x4*)(B1 + kk + 4);

        bf16x8 ah0, al0, ah1, al1, bh0, bl0, bh1, bl1;
        split8(a00, a01, ah0, al0);
        split8(a10, a11, ah1, al1);
        split8(b00, b01, bh0, bl0);
        split8(b10, b11, bh1, bl1);

        acc[0][0] = __builtin_amdgcn_mfma_f32_16x16x32_bf16(ah0, bh0, acc[0][0], 0, 0, 0);
        acc[0][0] = __builtin_amdgcn_mfma_f32_16x16x32_bf16(al0, bh0, acc[0][0], 0, 0, 0);
        acc[0][0] = __builtin_amdgcn_mfma_f32_16x16x32_bf16(ah0, bl0, acc[0][0], 0, 0, 0);
        acc[0][1] = __builtin_amdgcn_mfma_f32_16x16x32_bf16(ah0, bh1, acc[0][1], 0, 0, 0);
        acc[0][1] = __builtin_amdgcn_mfma_f32_16x16x32_bf16(al0, bh1, acc[0][1], 0, 0, 0);
        acc[0][1] = __builtin_amdgcn_mfma_f32_16x16x32_bf16(ah0, bl1, acc[0][1], 0, 0, 0);
        acc[1][0] = __builtin_amdgcn_mfma_f32_16x16x32_bf16(ah1, bh0, acc[1][0], 0, 0, 0);
        acc[1][0] = __builtin_amdgcn_mfma_f32_16x16x32_bf16(al1, bh0, acc[1][0], 0, 0, 0);
        acc[1][0] = __builtin_amdgcn_mfma_f32_16x16x32_bf16(ah1, bl0, acc[1][0], 0, 0, 0);
        acc[1][1] = __builtin_amdgcn_mfma_f32_16x16x32_bf16(ah1, bh1, acc[1][1], 0, 0, 0);
        acc[1][1] = __builtin_amdgcn_mfma_f32_16x16x32_bf16(al1, bh1, acc[1][1], 0, 0, 0);
        acc[1][1] = __builtin_amdgcn_mfma_f32_16x16x32_bf16(ah1, bl1, acc[1][1], 0, 0, 0);
    }

    // epilogue: C/D layout col=lane&15, row=quad*4+reg (m89/m91-verified)
#pragma unroll
    for (int ni = 0; ni < 2; ++ni) {
        const int col = n0 + wn + ni * 16 + l15;
        const float bb = bias[col];
#pragma unroll
        for (int mi = 0; mi < 2; ++mi) {
            const int row = m0 + wm + mi * 16 + quad * 4;
#pragma unroll
            for (int rr = 0; rr < 4; ++rr) {
                Y[(size_t)(row + rr) * D_SZ + col] = acc[mi][ni][rr] + bb;
            }
        }
    }
}

// ---------------------------------------------------------------------------
// Kernel 2: per batch b, f(s) = sum_j exp2(s*kL_j)*v_j / sum_j exp2(s*kL_j);
// out[b,i] = f(q_i). kL = k*log2e applied at LDS staging. Phase 1: f on a
// 64-pt uniform grid over [qmin,qmax]; 4 threads per grid point (each
// sweeps 128 j's, 2 shfl_xor combine). Phase 2: Lagrange-cubic interp.
// (Byte-identical to rounds 10/11 -- control variable this round.)
// ---------------------------------------------------------------------------
__global__ __launch_bounds__(256) void attn_kernel(
    const float* __restrict__ qkv, float* __restrict__ out)
{
    const int b = blockIdx.x;
    const int t = threadIdx.x;

    const float* __restrict__ q = qkv + (size_t)b * D_SZ;
    const float* __restrict__ k = qkv + (size_t)B_SZ * D_SZ + (size_t)b * D_SZ;
    const float* __restrict__ v = qkv + (size_t)2 * B_SZ * D_SZ + (size_t)b * D_SZ;

    __shared__ __align__(16) float kk_s[4 * SEG];
    __shared__ __align__(16) float vv_s[4 * SEG];
    __shared__ __align__(16) float fgrid[NGRID];
    __shared__ float redmax[4], redmin[4];

    // ---- stage k*log2e, v to LDS (segmented), load this thread's q rows ----
    const int i0 = t, i1 = t + 256;
    const float q0 = q[i0];
    const float q1 = q[i1];
    {
        const int j   = 2 * t;
        const int pos = (j >> 7) * SEG + (j & 127);
        float2 kf = *(const float2*)&k[j];
        float2 vf = *(const float2*)&v[j];
        kf.x *= LOG2E;
        kf.y *= LOG2E;
        *(float2*)&kk_s[pos] = kf;
        *(float2*)&vv_s[pos] = vf;
    }

    // ---- q-range reduction (grid support) ----
    float qmax = fmaxf(q0, q1), qmin = fminf(q0, q1);
#pragma unroll
    for (int off = 32; off > 0; off >>= 1) {
        qmax = fmaxf(qmax, __shfl_xor(qmax, off));
        qmin = fminf(qmin, __shfl_xor(qmin, off));
    }
    const int wave = t >> 6;
    if ((t & 63) == 0) { redmax[wave] = qmax; redmin[wave] = qmin; }
    __syncthreads();   // also publishes kk_s/vv_s
    qmax = fmaxf(fmaxf(redmax[0], redmax[1]), fmaxf(redmax[2], redmax[3]));
    qmin = fminf(fminf(redmin[0], redmin[1]), fminf(redmin[2], redmin[3]));

    const float h    = fmaxf((qmax - qmin) * (1.0f / (float)(NGRID - 3)), 1e-30f);
    const float s0   = qmin - h;                 // grid: s_g = s0 + g*h
    const float invh = 1.0f / h;                 // q in [s_1, s_{NGRID-2}]

    // ---- phase 1: grid evaluation (4 threads per grid point) ----
    {
        const int   g   = t >> 2;
        const int   sub = t & 3;
        const int   jb  = sub * SEG;
        const float sg  = s0 + (float)g * h;
        const f32x2 sgg = {sg, sg};

        f32x2 dena = {0.f, 0.f}, denb = {0.f, 0.f};
        f32x2 numa = {0.f, 0.f}, numb = {0.f, 0.f};
#pragma unroll 4
        for (int jj = 0; jj < 128; jj += 4) {
            f32x4 kq = *(const f32x4*)&kk_s[jb + jj];
            f32x4 vq = *(const f32x4*)&vv_s[jb + jj];
            f32x2 ka = {kq.x, kq.y}, kb_ = {kq.z, kq.w};
            f32x2 va = {vq.x, vq.y}, vb_ = {vq.z, vq.w};

            f32x2 ea = pk_mul(sgg, ka);
            f32x2 eb = pk_mul(sgg, kb_);
            // in-place v_exp_f32 on the pair's own registers (no repack)
            ea.x = exp2_raw(ea.x); ea.y = exp2_raw(ea.y);
            eb.x = exp2_raw(eb.x); eb.y = exp2_raw(eb.y);

            dena = pk_add(dena, ea);
            denb = pk_add(denb, eb);
            numa = pk_fma(ea, va, numa);
            numb = pk_fma(eb, vb_, numb);
        }
        float den = (dena.x + dena.y) + (denb.x + denb.y);
        float num = (numa.x + numa.y) + (numb.x + numb.y);
        den += __shfl_xor(den, 1);  num += __shfl_xor(num, 1);
        den += __shfl_xor(den, 2);  num += __shfl_xor(num, 2);
        if (sub == 0) fgrid[g] = num / den;
    }
    __syncthreads();

    // ---- phase 2: cubic interpolation at q_i ----
#pragma unroll
    for (int r = 0; r < 2; ++r) {
        const float qi = (r == 0) ? q0 : q1;
        const int   ii = (r == 0) ? i0 : i1;

        float u  = (qi - s0) * invh;
        int   ic = (int)floorf(u);
        ic = (ic < 1) ? 1 : ((ic > NGRID - 3) ? (NGRID - 3) : ic);
        float uu = u - (float)ic;

        float f0 = fgrid[ic - 1];
        float f1 = fgrid[ic];
        float f2 = fgrid[ic + 1];
        float f3 = fgrid[ic + 2];

        const float um1 = uu - 1.0f, um2 = uu - 2.0f, up1 = uu + 1.0f;
        const float w0 = -uu * um1 * um2 * (1.0f / 6.0f);
        const float w1 =  up1 * um1 * um2 * 0.5f;
        const float w2 = -up1 * uu  * um2 * 0.5f;
        const float w3 =  up1 * uu  * um1 * (1.0f / 6.0f);

        out[(size_t)b * D_SZ + ii] = w0 * f0 + w1 * f1 + w2 * f2 + w3 * f3;
    }
}

extern "C" void kernel_launch(void* const* d_in, const int* in_sizes, int n_in,
                              void* d_out, int out_size, void* d_ws, size_t ws_size,
                              hipStream_t stream) {
    const float* query = (const float*)d_in[0];
    const float* key_  = (const float*)d_in[1];
    const float* value = (const float*)d_in[2];
    const float* Wq    = (const float*)d_in[3];
    const float* bq    = (const float*)d_in[4];
    const float* Wk    = (const float*)d_in[5];
    const float* bk    = (const float*)d_in[6];
    const float* Wv    = (const float*)d_in[7];
    const float* bv    = (const float*)d_in[8];
    float* out = (float*)d_out;

    // workspace: qkv fp32 [3][B][D] = 12.58 MB
    float* qkv = (float*)d_ws;

    dim3 g1(B_SZ / 64, D_SZ / 64, 3);
    qkv_gemm_mfma<<<g1, 256, 0, stream>>>(query, key_, value, Wq, Wk, Wv,
                                          bq, bk, bv, qkv);

    attn_kernel<<<B_SZ, 256, 0, stream>>>(qkv, out);
}